// Round 14
// baseline (66.712 us; speedup 1.0000x reference)
//
#include <hip/hip_runtime.h>
#include <hip/hip_bf16.h>
#include <math.h>

#define BB 32
#define LL 2048
#define HH 1024
#define WPB 4                     // waves per block in pass 1
#define RPW 16                    // rows per wave
#define CPB (LL / (WPB * RPW))    // chunks (blocks) per batch = 32
#define WIB (CPB * WPB)           // waves per batch = 128 (row stride)

__device__ __forceinline__ float dot4(float4 a, float4 b) {
    return fmaf(a.x, b.x, fmaf(a.y, b.y, fmaf(a.z, b.z, a.w * b.w)));
}
__device__ __forceinline__ void scal4(float4& a, float s) {
    a.x *= s; a.y *= s; a.z *= s; a.w *= s;
}
__device__ __forceinline__ void fma4(float4& a, float p, float4 x) {
    a.x = fmaf(p, x.x, a.x); a.y = fmaf(p, x.y, a.y);
    a.z = fmaf(p, x.z, a.z); a.w = fmaf(p, x.w, a.w);
}
__device__ __forceinline__ void add4(float4& a, float4 x) {
    a.x += x.x; a.y += x.y; a.z += x.z; a.w += x.w;
}

// ---------------------------------------------------------------------------
// Pass 1: R9/R12-proven structure (65.8/65.9us). SINGLE LEVER: per-row
// __syncthreads() to keep the block's 4 waves phase-locked on a contiguous
// 16KB window (rows c*4..c*4+3 at step r). R9 showed stream coherence is
// worth real microseconds; without a barrier the sliding front smears over
// the 16 row-steps back toward scattered per-wave streams.
// Lessons pinned: NO nontemporal loads (R5). NO device fences (R6). NO
// explicit reg pipeline (R10: spill). Tail reads must stay float4 (R11).
// ---------------------------------------------------------------------------
__global__ __launch_bounds__(256, 4) void k_pass1(
    const float* __restrict__ ctx,   // [B,L,H]
    const float* __restrict__ cov,   // [B,L]
    const float* __restrict__ Ww,    // [H]
    const float* __restrict__ covw,  // [H]
    float* __restrict__ pbuf,        // [B,L]  p = exp(score)
    float* __restrict__ pz,          // [B,CPB]
    float* __restrict__ pacc)        // [B,CPB,H]
{
    const int b    = blockIdx.y;
    const int c    = blockIdx.x;            // chunk within b
    const int w    = threadIdx.x >> 6;      // wave 0..3
    const int lane = threadIdx.x & 63;
    const int j    = c * WPB + w;           // wave index within batch, 0..127

    const float4* wwf = (const float4*)Ww;
    float4 w0 = wwf[lane], w1 = wwf[64 + lane], w2 = wwf[128 + lane], w3 = wwf[192 + lane];
    const float4* cwf = (const float4*)covw;
    float c1 = dot4(cwf[lane], w0) + dot4(cwf[64 + lane], w1) +
               dot4(cwf[128 + lane], w2) + dot4(cwf[192 + lane], w3);
#pragma unroll
    for (int s = 32; s; s >>= 1) c1 += __shfl_xor(c1, s);

    float covchunk = (lane < RPW)
        ? cov[(size_t)b * LL + j + (size_t)lane * WIB] : 0.f;

    float Z = 0.f;
    float4 a0 = {0,0,0,0}, a1 = {0,0,0,0}, a2 = {0,0,0,0}, a3 = {0,0,0,0};
    float pkeep = 0.f;
    const float* base = ctx + ((size_t)b * LL + j) * HH;

#pragma unroll 4
    for (int r = 0; r < RPW; ++r) {
        const float4* row = (const float4*)(base + (size_t)r * WIB * HH);
        float4 x0 = row[lane], x1 = row[64 + lane], x2 = row[128 + lane], x3 = row[192 + lane];
        float d = dot4(x0, w0) + dot4(x1, w1) + dot4(x2, w2) + dot4(x3, w3);
#pragma unroll
        for (int s = 32; s; s >>= 1) d += __shfl_xor(d, s);
        float p = __expf(fmaf(c1, __shfl(covchunk, r), d));
        pkeep = (lane == r) ? p : pkeep;
        Z += p;
        fma4(a0, p, x0); fma4(a1, p, x1); fma4(a2, p, x2); fma4(a3, p, x3);
        __syncthreads();   // phase-lock the block's 4 waves -> tight 16KB window
    }

    if (lane < RPW)
        pbuf[(size_t)b * LL + j + (size_t)lane * WIB] = pkeep;

    // -------- in-block combine: 4 waves -> 1 partial --------
    __shared__ float sacc[WPB][HH];
    __shared__ float sZ[WPB];
    float4* ap = (float4*)&sacc[w][0];
    ap[lane] = a0; ap[64 + lane] = a1; ap[128 + lane] = a2; ap[192 + lane] = a3;
    if (lane == 0) sZ[w] = Z;
    __syncthreads();

    const int t = threadIdx.x;
    float4 v0 = ((const float4*)&sacc[0][0])[t];
    float4 v1 = ((const float4*)&sacc[1][0])[t];
    float4 v2 = ((const float4*)&sacc[2][0])[t];
    float4 v3 = ((const float4*)&sacc[3][0])[t];
    float4 v = { v0.x + v1.x + v2.x + v3.x, v0.y + v1.y + v2.y + v3.y,
                 v0.z + v1.z + v2.z + v3.z, v0.w + v1.w + v2.w + v3.w };
    ((float4*)(pacc + ((size_t)b * CPB + c) * HH))[t] = v;
    if (t == 0) pz[b * CPB + c] = sZ[0] + sZ[1] + sZ[2] + sZ[3];
}

// ---------------------------------------------------------------------------
// Pass 2: mix ONLY. Grid (B, 4): each block computes one 256-col quarter of
// mix[b] from the CPB partials (float4 reads, no redundancy).
// ---------------------------------------------------------------------------
__global__ __launch_bounds__(256) void k_combine(
    const float* __restrict__ pz, const float* __restrict__ pacc,
    float* __restrict__ mix)       // [B,H]
{
    const int b = blockIdx.x;
    const int y = blockIdx.y;
    const int t = threadIdx.x;
    __shared__ float zsh;
    __shared__ float4 red[4][64];

    if (t < 64) {
        float z = (t < CPB) ? pz[b * CPB + t] : 0.f;
#pragma unroll
        for (int s = 32; s; s >>= 1) z += __shfl_xor(z, s);
        if (t == 0) zsh = z;
    }
    __syncthreads();
    const float invZ = 1.f / zsh;

    const int col = y * 64 + (t & 63);   // float4 column
    const int g = t >> 6;                // chunk group 0..3
    const float4* pb = (const float4*)(pacc + (size_t)b * CPB * HH);
    float4 v = {0, 0, 0, 0};
#pragma unroll
    for (int i = g * 8; i < g * 8 + 8; ++i)
        add4(v, pb[(size_t)i * (HH / 4) + col]);
    red[g][t & 63] = v;
    __syncthreads();
    if (t < 64) {
        float4 s = red[0][t];
        add4(s, red[1][t]); add4(s, red[2][t]); add4(s, red[3][t]);
        scal4(s, invZ);
        ((float4*)(mix + (size_t)b * HH))[y * 64 + t] = s;
    }
}

// ---------------------------------------------------------------------------
// Pass 3: out[b,h] = tanh(sum_k combined[b,k]*W[k,h] + out_b[h]),
// combined = [mix | output]. k-split x32 (KC=64), h-chunks x8 (128 cols).
// ---------------------------------------------------------------------------
__global__ __launch_bounds__(256) void k_gemm_part(
    const float* __restrict__ mix,   // [B,H]
    const float* __restrict__ outp,  // [B,H]
    const float* __restrict__ W,     // [2H,H]
    float* __restrict__ part)        // [32,B,H]
{
    const int h0 = blockIdx.x * 128;
    const int kc = blockIdx.y;
    const int k0 = kc * 64;
    __shared__ float comb[64][40];   // [k][b], padded

    const int t = threadIdx.x;
    {
        const int kk = t & 63;
        const int bb = t >> 6;       // 0..3
        const float* src = (k0 < HH) ? (mix + k0) : (outp + (k0 - HH));
        for (int b2 = bb; b2 < BB; b2 += 4)
            comb[kk][b2] = src[(size_t)b2 * HH + kk];
    }
    __syncthreads();

    const int hg = t & 31;           // 4 consecutive cols
    const int bg = t >> 5;           // 0..7 -> 4 consecutive b's
    const float* Wp = W + (size_t)k0 * HH + h0 + hg * 4;

    float4 acc0 = {0,0,0,0}, acc1 = {0,0,0,0}, acc2 = {0,0,0,0}, acc3 = {0,0,0,0};
#pragma unroll 4
    for (int kk = 0; kk < 64; ++kk) {
        float4 c = *(const float4*)&comb[kk][bg * 4];
        float4 w = *(const float4*)(Wp + (size_t)kk * HH);
        fma4(acc0, c.x, w); fma4(acc1, c.y, w);
        fma4(acc2, c.z, w); fma4(acc3, c.w, w);
    }

    float* pp = part + ((size_t)kc * BB + bg * 4) * HH + h0 + hg * 4;
    *(float4*)(pp + 0 * HH) = acc0;
    *(float4*)(pp + 1 * HH) = acc1;
    *(float4*)(pp + 2 * HH) = acc2;
    *(float4*)(pp + 3 * HH) = acc3;
}

// ---------------------------------------------------------------------------
// Pass 4: grid 96. Blocks 0-63: gemm kc-reduce + tanh (2 threads/output,
// shfl_xor(1) combine). Blocks 64-95: attn + coverage_new for b = blk-64.
// ---------------------------------------------------------------------------
__global__ __launch_bounds__(256) void k_final(
    const float* __restrict__ part,  // [32,B,H]
    const float* __restrict__ outb,  // [H]
    const float* __restrict__ pz,    // [B,CPB]
    const float* __restrict__ pbuf,  // [B,L]
    const float* __restrict__ cov,   // [B,L]
    float* __restrict__ out0,        // [B,H]
    float* __restrict__ out_attn,    // [B,L]
    float* __restrict__ out_cov)     // [B,L]
{
    const int t = threadIdx.x;
    if (blockIdx.x < 64) {
        const int g = blockIdx.x * 256 + t;
        const int o = g >> 1;            // output float4 id
        const int half = g & 1;
        const int b  = o >> 8;
        const int h4 = o & 255;
        float4 s = {0, 0, 0, 0};
#pragma unroll
        for (int kc = half * 16; kc < half * 16 + 16; ++kc)
            add4(s, ((const float4*)part)[((size_t)kc * BB + b) * 256 + h4]);
        s.x += __shfl_xor(s.x, 1);
        s.y += __shfl_xor(s.y, 1);
        s.z += __shfl_xor(s.z, 1);
        s.w += __shfl_xor(s.w, 1);
        if (half == 0) {
            float4 bb = ((const float4*)outb)[h4];
            float4 o4;
            o4.x = tanhf(s.x + bb.x); o4.y = tanhf(s.y + bb.y);
            o4.z = tanhf(s.z + bb.z); o4.w = tanhf(s.w + bb.w);
            ((float4*)out0)[o] = o4;
        }
    } else {
        const int b = blockIdx.x - 64;
        __shared__ float zsh;
        if (t < 64) {
            float z = (t < CPB) ? pz[b * CPB + t] : 0.f;
#pragma unroll
            for (int s = 32; s; s >>= 1) z += __shfl_xor(z, s);
            if (t == 0) zsh = z;
        }
        __syncthreads();
        const float invZ = 1.f / zsh;

        const float4* pb4 = (const float4*)(pbuf + (size_t)b * LL);
        const float4* cv4 = (const float4*)(cov + (size_t)b * LL);
        float4* oa4 = (float4*)(out_attn + (size_t)b * LL);
        float4* oc4 = (float4*)(out_cov + (size_t)b * LL);
#pragma unroll
        for (int i = t; i < LL / 4; i += 256) {
            float4 p = pb4[i];
            scal4(p, invZ);
            oa4[i] = p;
            float4 cvv = cv4[i];
            add4(cvv, p);
            oc4[i] = cvv;
        }
    }
}

extern "C" void kernel_launch(void* const* d_in, const int* in_sizes, int n_in,
                              void* d_out, int out_size, void* d_ws, size_t ws_size,
                              hipStream_t stream) {
    const float* outp = (const float*)d_in[0];  // [B,1,H]
    const float* ctx  = (const float*)d_in[1];  // [B,L,H]
    const float* cov  = (const float*)d_in[2];  // [B,L]
    const float* Ww   = (const float*)d_in[3];  // [H]
    const float* covw = (const float*)d_in[5];  // [H]
    const float* outw = (const float*)d_in[7];  // [2H,H]
    const float* outb = (const float*)d_in[8];  // [H]

    float* out0     = (float*)d_out;            // [B,1,H]
    float* out_attn = out0 + BB * HH;           // [B,1,L]
    float* out_cov  = out_attn + BB * LL;       // [B,L]

    float* w = (float*)d_ws;
    float* pbuf = w;  w += (size_t)BB * LL;          // 64K floats
    float* pz   = w;  w += (size_t)BB * CPB;         // 1K
    float* pacc = w;  w += (size_t)BB * CPB * HH;    // 1M
    float* mix  = w;  w += (size_t)BB * HH;          // 32K
    float* part = w;                                  // 1M

    dim3 g1(CPB, BB);
    k_pass1<<<g1, 256, 0, stream>>>(ctx, cov, Ww, covw, pbuf, pz, pacc);
    dim3 g2(BB, 4);
    k_combine<<<g2, 256, 0, stream>>>(pz, pacc, mix);
    dim3 g3(8, 32);
    k_gemm_part<<<g3, 256, 0, stream>>>(mix, outp, outw, part);
    k_final<<<96, 256, 0, stream>>>(part, outb, pz, pbuf, cov, out0, out_attn, out_cov);
}

// Round 15
// 65.356 us; speedup vs baseline: 1.0208x; 1.0208x over previous
//
#include <hip/hip_runtime.h>
#include <hip/hip_bf16.h>
#include <math.h>

#define BB 32
#define LL 2048
#define HH 1024
#define WPB 4                     // waves per block in pass 1
#define RPW 16                    // rows per wave
#define CPB (LL / (WPB * RPW))    // chunks (blocks) per batch = 32
#define WIB (CPB * WPB)           // waves per batch = 128 (row stride)

__device__ __forceinline__ float dot4(float4 a, float4 b) {
    return fmaf(a.x, b.x, fmaf(a.y, b.y, fmaf(a.z, b.z, a.w * b.w)));
}
__device__ __forceinline__ void scal4(float4& a, float s) {
    a.x *= s; a.y *= s; a.z *= s; a.w *= s;
}
__device__ __forceinline__ void fma4(float4& a, float p, float4 x) {
    a.x = fmaf(p, x.x, a.x); a.y = fmaf(p, x.y, a.y);
    a.z = fmaf(p, x.z, a.z); a.w = fmaf(p, x.w, a.w);
}
__device__ __forceinline__ void add4(float4& a, float4 x) {
    a.x += x.x; a.y += x.y; a.z += x.z; a.w += x.w;
}

// ---------------------------------------------------------------------------
// Pass 1 (R9/R12-proven best, 65.8/65.9us — byte-identical): single
// streaming pass, branchless fixed-shift softmax (m=0; scores bounded
// ~[-4,4], softmax renormalizes). Strided row->wave mapping (sliding read
// fronts; +3.5us). 4 waves x 16 rows, unroll 4. In-block LDS combine.
// Refuted levers (do not retry): NT loads (R5: ~500 GB/s), device fences
// (R6: ~200us L2 flushes), explicit reg pipeline (R10: scratch spill),
// occupancy bump (R7: null, queue already full), per-row barrier (R13:
// null — front-smear hypothesis false), scalar-width tail fusion (R11).
// ---------------------------------------------------------------------------
__global__ __launch_bounds__(256, 4) void k_pass1(
    const float* __restrict__ ctx,   // [B,L,H]
    const float* __restrict__ cov,   // [B,L]
    const float* __restrict__ Ww,    // [H]
    const float* __restrict__ covw,  // [H]
    float* __restrict__ pbuf,        // [B,L]  p = exp(score)
    float* __restrict__ pz,          // [B,CPB]
    float* __restrict__ pacc)        // [B,CPB,H]
{
    const int b    = blockIdx.y;
    const int c    = blockIdx.x;            // chunk within b
    const int w    = threadIdx.x >> 6;      // wave 0..3
    const int lane = threadIdx.x & 63;
    const int j    = c * WPB + w;           // wave index within batch, 0..127

    const float4* wwf = (const float4*)Ww;
    float4 w0 = wwf[lane], w1 = wwf[64 + lane], w2 = wwf[128 + lane], w3 = wwf[192 + lane];
    const float4* cwf = (const float4*)covw;
    float c1 = dot4(cwf[lane], w0) + dot4(cwf[64 + lane], w1) +
               dot4(cwf[128 + lane], w2) + dot4(cwf[192 + lane], w3);
#pragma unroll
    for (int s = 32; s; s >>= 1) c1 += __shfl_xor(c1, s);

    float covchunk = (lane < RPW)
        ? cov[(size_t)b * LL + j + (size_t)lane * WIB] : 0.f;

    float Z = 0.f;
    float4 a0 = {0,0,0,0}, a1 = {0,0,0,0}, a2 = {0,0,0,0}, a3 = {0,0,0,0};
    float pkeep = 0.f;
    const float* base = ctx + ((size_t)b * LL + j) * HH;

#pragma unroll 4
    for (int r = 0; r < RPW; ++r) {
        const float4* row = (const float4*)(base + (size_t)r * WIB * HH);
        float4 x0 = row[lane], x1 = row[64 + lane], x2 = row[128 + lane], x3 = row[192 + lane];
        float d = dot4(x0, w0) + dot4(x1, w1) + dot4(x2, w2) + dot4(x3, w3);
#pragma unroll
        for (int s = 32; s; s >>= 1) d += __shfl_xor(d, s);
        float p = __expf(fmaf(c1, __shfl(covchunk, r), d));
        pkeep = (lane == r) ? p : pkeep;
        Z += p;
        fma4(a0, p, x0); fma4(a1, p, x1); fma4(a2, p, x2); fma4(a3, p, x3);
    }

    if (lane < RPW)
        pbuf[(size_t)b * LL + j + (size_t)lane * WIB] = pkeep;

    // -------- in-block combine: 4 waves -> 1 partial --------
    __shared__ float sacc[WPB][HH];
    __shared__ float sZ[WPB];
    float4* ap = (float4*)&sacc[w][0];
    ap[lane] = a0; ap[64 + lane] = a1; ap[128 + lane] = a2; ap[192 + lane] = a3;
    if (lane == 0) sZ[w] = Z;
    __syncthreads();

    const int t = threadIdx.x;
    float4 v0 = ((const float4*)&sacc[0][0])[t];
    float4 v1 = ((const float4*)&sacc[1][0])[t];
    float4 v2 = ((const float4*)&sacc[2][0])[t];
    float4 v3 = ((const float4*)&sacc[3][0])[t];
    float4 v = { v0.x + v1.x + v2.x + v3.x, v0.y + v1.y + v2.y + v3.y,
                 v0.z + v1.z + v2.z + v3.z, v0.w + v1.w + v2.w + v3.w };
    ((float4*)(pacc + ((size_t)b * CPB + c) * HH))[t] = v;
    if (t == 0) pz[b * CPB + c] = sZ[0] + sZ[1] + sZ[2] + sZ[3];
}

// ---------------------------------------------------------------------------
// Pass 2: mix ONLY. Grid (B, 4): each block computes one 256-col quarter of
// mix[b] from the CPB partials (float4 reads, no redundancy).
// ---------------------------------------------------------------------------
__global__ __launch_bounds__(256) void k_combine(
    const float* __restrict__ pz, const float* __restrict__ pacc,
    float* __restrict__ mix)       // [B,H]
{
    const int b = blockIdx.x;
    const int y = blockIdx.y;
    const int t = threadIdx.x;
    __shared__ float zsh;
    __shared__ float4 red[4][64];

    if (t < 64) {
        float z = (t < CPB) ? pz[b * CPB + t] : 0.f;
#pragma unroll
        for (int s = 32; s; s >>= 1) z += __shfl_xor(z, s);
        if (t == 0) zsh = z;
    }
    __syncthreads();
    const float invZ = 1.f / zsh;

    const int col = y * 64 + (t & 63);   // float4 column
    const int g = t >> 6;                // chunk group 0..3
    const float4* pb = (const float4*)(pacc + (size_t)b * CPB * HH);
    float4 v = {0, 0, 0, 0};
#pragma unroll
    for (int i = g * 8; i < g * 8 + 8; ++i)
        add4(v, pb[(size_t)i * (HH / 4) + col]);
    red[g][t & 63] = v;
    __syncthreads();
    if (t < 64) {
        float4 s = red[0][t];
        add4(s, red[1][t]); add4(s, red[2][t]); add4(s, red[3][t]);
        scal4(s, invZ);
        ((float4*)(mix + (size_t)b * HH))[y * 64 + t] = s;
    }
}

// ---------------------------------------------------------------------------
// Pass 3: out[b,h] = tanh(sum_k combined[b,k]*W[k,h] + out_b[h]),
// combined = [mix | output]. k-split x32 (KC=64), h-chunks x8 (128 cols).
// ---------------------------------------------------------------------------
__global__ __launch_bounds__(256) void k_gemm_part(
    const float* __restrict__ mix,   // [B,H]
    const float* __restrict__ outp,  // [B,H]
    const float* __restrict__ W,     // [2H,H]
    float* __restrict__ part)        // [32,B,H]
{
    const int h0 = blockIdx.x * 128;
    const int kc = blockIdx.y;
    const int k0 = kc * 64;
    __shared__ float comb[64][40];   // [k][b], padded

    const int t = threadIdx.x;
    {
        const int kk = t & 63;
        const int bb = t >> 6;       // 0..3
        const float* src = (k0 < HH) ? (mix + k0) : (outp + (k0 - HH));
        for (int b2 = bb; b2 < BB; b2 += 4)
            comb[kk][b2] = src[(size_t)b2 * HH + kk];
    }
    __syncthreads();

    const int hg = t & 31;           // 4 consecutive cols
    const int bg = t >> 5;           // 0..7 -> 4 consecutive b's
    const float* Wp = W + (size_t)k0 * HH + h0 + hg * 4;

    float4 acc0 = {0,0,0,0}, acc1 = {0,0,0,0}, acc2 = {0,0,0,0}, acc3 = {0,0,0,0};
#pragma unroll 4
    for (int kk = 0; kk < 64; ++kk) {
        float4 c = *(const float4*)&comb[kk][bg * 4];
        float4 w = *(const float4*)(Wp + (size_t)kk * HH);
        fma4(acc0, c.x, w); fma4(acc1, c.y, w);
        fma4(acc2, c.z, w); fma4(acc3, c.w, w);
    }

    float* pp = part + ((size_t)kc * BB + bg * 4) * HH + h0 + hg * 4;
    *(float4*)(pp + 0 * HH) = acc0;
    *(float4*)(pp + 1 * HH) = acc1;
    *(float4*)(pp + 2 * HH) = acc2;
    *(float4*)(pp + 3 * HH) = acc3;
}

// ---------------------------------------------------------------------------
// Pass 4: grid 96. Blocks 0-63: gemm kc-reduce + tanh (2 threads/output,
// shfl_xor(1) combine). Blocks 64-95: attn + coverage_new for b = blk-64.
// ---------------------------------------------------------------------------
__global__ __launch_bounds__(256) void k_final(
    const float* __restrict__ part,  // [32,B,H]
    const float* __restrict__ outb,  // [H]
    const float* __restrict__ pz,    // [B,CPB]
    const float* __restrict__ pbuf,  // [B,L]
    const float* __restrict__ cov,   // [B,L]
    float* __restrict__ out0,        // [B,H]
    float* __restrict__ out_attn,    // [B,L]
    float* __restrict__ out_cov)     // [B,L]
{
    const int t = threadIdx.x;
    if (blockIdx.x < 64) {
        const int g = blockIdx.x * 256 + t;
        const int o = g >> 1;            // output float4 id
        const int half = g & 1;
        const int b  = o >> 8;
        const int h4 = o & 255;
        float4 s = {0, 0, 0, 0};
#pragma unroll
        for (int kc = half * 16; kc < half * 16 + 16; ++kc)
            add4(s, ((const float4*)part)[((size_t)kc * BB + b) * 256 + h4]);
        s.x += __shfl_xor(s.x, 1);
        s.y += __shfl_xor(s.y, 1);
        s.z += __shfl_xor(s.z, 1);
        s.w += __shfl_xor(s.w, 1);
        if (half == 0) {
            float4 bb = ((const float4*)outb)[h4];
            float4 o4;
            o4.x = tanhf(s.x + bb.x); o4.y = tanhf(s.y + bb.y);
            o4.z = tanhf(s.z + bb.z); o4.w = tanhf(s.w + bb.w);
            ((float4*)out0)[o] = o4;
        }
    } else {
        const int b = blockIdx.x - 64;
        __shared__ float zsh;
        if (t < 64) {
            float z = (t < CPB) ? pz[b * CPB + t] : 0.f;
#pragma unroll
            for (int s = 32; s; s >>= 1) z += __shfl_xor(z, s);
            if (t == 0) zsh = z;
        }
        __syncthreads();
        const float invZ = 1.f / zsh;

        const float4* pb4 = (const float4*)(pbuf + (size_t)b * LL);
        const float4* cv4 = (const float4*)(cov + (size_t)b * LL);
        float4* oa4 = (float4*)(out_attn + (size_t)b * LL);
        float4* oc4 = (float4*)(out_cov + (size_t)b * LL);
#pragma unroll
        for (int i = t; i < LL / 4; i += 256) {
            float4 p = pb4[i];
            scal4(p, invZ);
            oa4[i] = p;
            float4 cvv = cv4[i];
            add4(cvv, p);
            oc4[i] = cvv;
        }
    }
}

extern "C" void kernel_launch(void* const* d_in, const int* in_sizes, int n_in,
                              void* d_out, int out_size, void* d_ws, size_t ws_size,
                              hipStream_t stream) {
    const float* outp = (const float*)d_in[0];  // [B,1,H]
    const float* ctx  = (const float*)d_in[1];  // [B,L,H]
    const float* cov  = (const float*)d_in[2];  // [B,L]
    const float* Ww   = (const float*)d_in[3];  // [H]
    const float* covw = (const float*)d_in[5];  // [H]
    const float* outw = (const float*)d_in[7];  // [2H,H]
    const float* outb = (const float*)d_in[8];  // [H]

    float* out0     = (float*)d_out;            // [B,1,H]
    float* out_attn = out0 + BB * HH;           // [B,1,L]
    float* out_cov  = out_attn + BB * LL;       // [B,L]

    float* w = (float*)d_ws;
    float* pbuf = w;  w += (size_t)BB * LL;          // 64K floats
    float* pz   = w;  w += (size_t)BB * CPB;         // 1K
    float* pacc = w;  w += (size_t)BB * CPB * HH;    // 1M
    float* mix  = w;  w += (size_t)BB * HH;          // 32K
    float* part = w;                                  // 1M

    dim3 g1(CPB, BB);
    k_pass1<<<g1, 256, 0, stream>>>(ctx, cov, Ww, covw, pbuf, pz, pacc);
    dim3 g2(BB, 4);
    k_combine<<<g2, 256, 0, stream>>>(pz, pacc, mix);
    dim3 g3(8, 32);
    k_gemm_part<<<g3, 256, 0, stream>>>(mix, outp, outw, part);
    k_final<<<96, 256, 0, stream>>>(part, outb, pz, pbuf, cov, out0, out_attn, out_cov);
}